// Round 8
// baseline (143.212 us; speedup 1.0000x reference)
//
#include <hip/hip_runtime.h>
#include <math.h>

#ifndef M_PI
#define M_PI 3.14159265358979323846
#endif

#define LUT_N 4096
#define WVS 2   // waves per block (each fully independent until final merge)

// nearest-entry LUT cos, replicating jnp round-half-even + float mod semantics
__device__ __forceinline__ float lut_cos(float theta) {
    const float IDX_SCALE = (float)((double)LUT_N / (2.0 * M_PI)); // fl(4096/2pi)
    const float STEP = (float)((2.0 * M_PI) / (double)LUT_N);      // fl(2pi/4096)
    float x = theta * IDX_SCALE;
    int i = (int)rintf(x);     // round-half-even, matches jnp.round/np.round
    i &= (LUT_N - 1);          // == Python mod for pow2 in two's complement
    return cosf((float)i * STEP);
}

__global__ void qgen_kernel(const float* __restrict__ cur_r,
                            const float* __restrict__ cur_i,
                            const float* __restrict__ w_q,
                            const float* __restrict__ b_q,
                            const float* __restrict__ t_ptr,
                            float* __restrict__ q_out,
                            int B, int D) {
    int idx = blockIdx.x * blockDim.x + threadIdx.x;
    int twoD = 2 * D;
    if (idx >= B * twoD) return;
    int b = idx / twoD;
    int c = idx - b * twoD;
    int col = (c < D) ? c : c - D;
    const float* src = (c < D) ? cur_r : cur_i;
    float v = src[(size_t)b * D + col];
    float t_phi = t_ptr[0] * 1.61803398874989484820f;  // f32(PHI), f32 multiply
    float wl = 1.0f + fabsf(w_q[col]);
    float theta = v / wl + b_q[col] + t_phi;           // same op order as ref
    q_out[idx] = lut_cos(theta);
}

// Issue one full 4096-f32 row (real+imag halves) as 16 named-register
// global_load_dwordx4; vmcnt counted by hand at call sites.
__device__ __forceinline__ void issue_row(float4 (&kv)[16],
                                          const float* hr_row,
                                          const float* hi_row, int lane) {
#pragma unroll
    for (int j = 0; j < 8; ++j)
        asm volatile("global_load_dwordx4 %0, %1, off"
                     : "=&v"(kv[j])
                     : "v"(hr_row + j * 256 + lane * 4));
#pragma unroll
    for (int j = 0; j < 8; ++j)
        asm volatile("global_load_dwordx4 %0, %1, off"
                     : "=&v"(kv[8 + j])
                     : "v"(hi_row + j * 256 + lane * 4));
}

#define WAITV(N) do { \
    asm volatile("s_waitcnt vmcnt(" #N ")" ::: "memory"); \
    __builtin_amdgcn_sched_barrier(0); } while (0)

// dot + online-softmax update; rv accumulator lives in per-wave LDS
// (frees 64 VGPRs so kvA/kvB can never spill).
__device__ __forceinline__ void proc_row(const float4 (&kv)[16],
                                         const float4* qsh,   // block-shared q
                                         float4* rp,          // this wave's rv
                                         int lane, float& m0, float& l) {
    float p0 = 0.f, p1 = 0.f, p2 = 0.f, p3 = 0.f;
#pragma unroll
    for (int k = 0; k < 4; ++k) {
        float4 qa = qsh[(4 * k + 0) * 64 + lane];
        float4 qb = qsh[(4 * k + 1) * 64 + lane];
        float4 qc = qsh[(4 * k + 2) * 64 + lane];
        float4 qd = qsh[(4 * k + 3) * 64 + lane];
        p0 += qa.x * kv[4*k+0].x + qa.y * kv[4*k+0].y +
              qa.z * kv[4*k+0].z + qa.w * kv[4*k+0].w;
        p1 += qb.x * kv[4*k+1].x + qb.y * kv[4*k+1].y +
              qb.z * kv[4*k+1].z + qb.w * kv[4*k+1].w;
        p2 += qc.x * kv[4*k+2].x + qc.y * kv[4*k+2].y +
              qc.z * kv[4*k+2].z + qc.w * kv[4*k+2].w;
        p3 += qd.x * kv[4*k+3].x + qd.y * kv[4*k+3].y +
              qd.z * kv[4*k+3].z + qd.w * kv[4*k+3].w;
    }
    float p = (p0 + p1) + (p2 + p3);
#pragma unroll
    for (int off = 32; off; off >>= 1) p += __shfl_xor(p, off);
    float sc = p * (1.0f / 64.0f);       // 1/sqrt(2*2048), exact; wave-uniform

    float d = sc - m0;
    float w;
    if (d > 8.0f) {                      // rare, wave-uniform; first row: d=+inf
        float corr = __expf(-d);         // first row: exp(-inf) = 0
        l *= corr;
#pragma unroll
        for (int k = 0; k < 16; ++k) {
            float4 v = rp[k * 64 + lane];
            v.x *= corr; v.y *= corr; v.z *= corr; v.w *= corr;
            rp[k * 64 + lane] = v;
        }
        m0 = sc;
        w = 1.0f;
    } else {
        w = __expf(d);                   // bounded by e^8
    }
    l += w;
#pragma unroll
    for (int k = 0; k < 16; ++k) {
        float4 v = rp[k * 64 + lane];
        v.x = fmaf(w, kv[k].x, v.x);
        v.y = fmaf(w, kv[k].y, v.y);
        v.z = fmaf(w, kv[k].z, v.z);
        v.w = fmaf(w, kv[k].w, v.w);
        rp[k * 64 + lane] = v;
    }
}

// Wave-autonomous flash: depth-2 named-register load pipeline (kvA/kvB =
// 128 VGPR), rv accumulator in per-wave LDS, q in block-shared LDS.
// Zero barriers in the row loop; hand vmcnt(16). 2-wave merge at end.
// Requires 2D == 4096.
__global__ __launch_bounds__(128, 2) void flash_kernel(
    const float* __restrict__ hist_r,
    const float* __restrict__ hist_i,
    const float* __restrict__ q_ws,
    float* __restrict__ r_ws,
    float* __restrict__ ml_ws,
    int H, int Wb, int bpb) {
    const int t = threadIdx.x;
    const int lane = t & 63;
    const int wv = t >> 6;                        // 0..1
    const int b = blockIdx.x / bpb;
    const int j = (blockIdx.x - b * bpb) * WVS + wv;  // wave-in-batch, 0..Wb-1

    __shared__ float4 qsh[1024];                  // 16 KB block-shared q
    __shared__ float4 rvb[WVS][1024];             // 32 KB per-wave accumulators
    __shared__ float sm[WVS], sl[WVS];

    // cooperative q stage -> LDS (128 threads x 8 float4); zero my rv
    const float4* q4 = (const float4*)q_ws + (size_t)b * 1024;
#pragma unroll
    for (int k = 0; k < 8; ++k) qsh[t + 128 * k] = q4[t + 128 * k];
    float4* rp = &rvb[wv][0];
#pragma unroll
    for (int k = 0; k < 16; ++k)
        rp[k * 64 + lane] = make_float4(0.f, 0.f, 0.f, 0.f);
    __syncthreads();                              // also drains vmcnt to 0

    const int n = (H - j + Wb - 1) / Wb;          // rows for this wave (21/22)
    const size_t step = (size_t)Wb * 2048;
    const float* hr = hist_r + ((size_t)b * H + j) * 2048;
    const float* hi = hist_i + ((size_t)b * H + j) * 2048;

    float m0 = -INFINITY, l = 0.f;
    float4 kvA[16], kvB[16];
    if (n > 0) issue_row(kvA, hr, hi, lane);
    if (n > 1) issue_row(kvB, hr + step, hi + step, lane);

    int i = 0;
    for (; i + 2 < n; i += 2) {
        WAITV(16);                                // row i (kvA) landed
        proc_row(kvA, qsh, rp, lane, m0, l);
        issue_row(kvA, hr + (size_t)(i + 2) * step, hi + (size_t)(i + 2) * step, lane);
        WAITV(16);                                // row i+1 (kvB) landed
        proc_row(kvB, qsh, rp, lane, m0, l);
        if (i + 3 < n)
            issue_row(kvB, hr + (size_t)(i + 3) * step, hi + (size_t)(i + 3) * step, lane);
    }
    if (n - i == 2) {
        WAITV(16);
        proc_row(kvA, qsh, rp, lane, m0, l);
        WAITV(0);
        proc_row(kvB, qsh, rp, lane, m0, l);
    } else if (n - i == 1) {
        WAITV(0);
        proc_row(kvA, qsh, rp, lane, m0, l);
    }

    // ---- 2-wave merge ----
    if (lane == 0) { sm[wv] = m0; sl[wv] = l; }
    __syncthreads();
    float M = fmaxf(sm[0], sm[1]);
    float Lb = sl[0] * __expf(sm[0] - M) + sl[1] * __expf(sm[1] - M);
    float scale = __expf(m0 - M);                 // per-wave rescale to block max
#pragma unroll
    for (int k = 0; k < 16; ++k) {
        float4 v = rp[k * 64 + lane];
        v.x *= scale; v.y *= scale; v.z *= scale; v.w *= scale;
        rp[k * 64 + lane] = v;
    }
    __syncthreads();

    float4* ro = (float4*)r_ws + (size_t)blockIdx.x * 1024;
    for (int k = t; k < 1024; k += 128) {
        float4 a = rvb[0][k], c = rvb[1][k];
        ro[k] = make_float4(a.x + c.x, a.y + c.y, a.z + c.z, a.w + c.w);
    }
    if (t == 0) {
        ml_ws[2 * (size_t)blockIdx.x] = M;
        ml_ws[2 * (size_t)blockIdx.x + 1] = Lb;
    }
}

// grid = B * (2D/256) blocks; each thread owns one output column.
__global__ void combine_kernel(const float* __restrict__ r_ws,
                               const float* __restrict__ ml_ws,
                               const float* __restrict__ ema,
                               const float* __restrict__ alpha_ptr,
                               float* __restrict__ out,
                               int D, int S) {
    const int twoD = 2 * D;
    const int nc = twoD / 256;
    const int b = blockIdx.x / nc;
    const int cb = blockIdx.x - b * nc;
    const int c = cb * 256 + threadIdx.x;

    const float* ml = ml_ws + (size_t)b * S * 2;
    float M = -INFINITY;
    for (int s = 0; s < S; ++s) M = fmaxf(M, ml[2 * s]);
    float L = 0.f;
    for (int s = 0; s < S; ++s) L += ml[2 * s + 1] * __expf(ml[2 * s] - M);

    float acc = 0.f;
    const float* rb = r_ws + (size_t)b * S * twoD + c;
    for (int s = 0; s < S; ++s)
        acc = fmaf(__expf(ml[2 * s] - M), rb[(size_t)s * twoD], acc);

    float a = 1.0f / (1.0f + __expf(-alpha_ptr[0]));  // sigmoid(alpha)
    float retrieved = acc / L;
    size_t o = (size_t)b * twoD + c;
    out[o] = a * retrieved + (1.0f - a) * ema[o];
}

extern "C" void kernel_launch(void* const* d_in, const int* in_sizes, int n_in,
                              void* d_out, int out_size, void* d_ws, size_t ws_size,
                              hipStream_t stream) {
    const float* cur_r  = (const float*)d_in[0];
    const float* cur_i  = (const float*)d_in[1];
    const float* hist_r = (const float*)d_in[2];
    const float* hist_i = (const float*)d_in[3];
    const float* ema    = (const float*)d_in[4];
    const float* w_q    = (const float*)d_in[5];
    const float* b_q    = (const float*)d_in[6];
    const float* alpha  = (const float*)d_in[7];
    const float* t      = (const float*)d_in[8];

    const int D = in_sizes[5];                 // 2048
    const int B = in_sizes[0] / D;             // 16
    const int H = in_sizes[2] / (B * D);       // 2048
    const int twoD = 2 * D;

    float* q_ws = (float*)d_ws;
    size_t q_elems = (size_t)B * twoD;

    // 768 blocks total (3/CU at 48KB LDS), 2 waves each
    int bpb = 768 / B; if (bpb < 1) bpb = 1;   // 48
    while (bpb > 1) {
        size_t need = (q_elems + (size_t)B * bpb * twoD + (size_t)B * bpb * 2) * sizeof(float);
        if (need <= ws_size) break;
        bpb >>= 1;
    }
    const int Wb = bpb * WVS;                  // waves per batch (96)
    float* r_ws = q_ws + q_elems;
    float* ml_ws = r_ws + (size_t)B * bpb * twoD;

    int qblocks = (B * twoD + 255) / 256;
    qgen_kernel<<<qblocks, 256, 0, stream>>>(cur_r, cur_i, w_q, b_q, t, q_ws, B, D);
    flash_kernel<<<B * bpb, WVS * 64, 0, stream>>>(hist_r, hist_i, q_ws, r_ws, ml_ws,
                                                   H, Wb, bpb);
    combine_kernel<<<B * (twoD / 256), 256, 0, stream>>>(r_ws, ml_ws, ema, alpha,
                                                         (float*)d_out, D, bpb);
}